// Round 10
// baseline (8446.150 us; speedup 1.0000x reference)
//
#include <hip/hip_runtime.h>
#include <math.h>

#define N_NODES 100000
#define N_EDGES 1600000
#define HDIM 64
#define SCAN_T 1024
#define SCAN_CHUNK 98    // ceil(100000/1024)
#define NPB 64           // nodes per block in k_layer
#define LBLOCKS 1563     // ceil(100000/64)

// order-preserving float<->uint map: min-uint == min-float (non-NaN)
__device__ __forceinline__ unsigned encMin(float f) {
  unsigned u = __float_as_uint(f);
  return (u & 0x80000000u) ? ~u : (u | 0x80000000u);
}
__device__ __forceinline__ float decMin(unsigned u) {
  unsigned b = (u & 0x80000000u) ? (u & 0x7FFFFFFFu) : ~u;
  return __uint_as_float(b);
}

// ---------------- CSR build ----------------

__global__ __launch_bounds__(256) void k_zero_int(int* __restrict__ p, int n) {
  int i = blockIdx.x * 256 + threadIdx.x;
  if (i < n) p[i] = 0;
}

__global__ __launch_bounds__(256) void k_deg_count(const int* __restrict__ ei,
                                                   int* __restrict__ deg) {
  int e = blockIdx.x * 256 + threadIdx.x;
  if (e < N_EDGES) atomicAdd(&deg[ei[N_EDGES + e]], 1);
}

// single-block exclusive scan of deg[N] -> row_ptr[N+1]
__global__ __launch_bounds__(SCAN_T) void k_rowptr(const int* __restrict__ deg,
                                                   int* __restrict__ row_ptr) {
  __shared__ int sums[SCAN_T];
  const int t = threadIdx.x;
  const int lo = t * SCAN_CHUNK;
  const int hi = min(lo + SCAN_CHUNK, N_NODES);
  int s = 0;
  for (int i = lo; i < hi; ++i) s += deg[i];
  sums[t] = s;
  __syncthreads();
  for (int off = 1; off < SCAN_T; off <<= 1) {
    int v = (t >= off) ? sums[t - off] : 0;
    __syncthreads();
    sums[t] += v;
    __syncthreads();
  }
  int run = (t == 0) ? 0 : sums[t - 1];
  for (int i = lo; i < hi; ++i) { row_ptr[i] = run; run += deg[i]; }
  if (t == SCAN_T - 1) row_ptr[N_NODES] = run;
}

// pack src (20 bits) | node-local dst (6 bits << 20)
__global__ __launch_bounds__(256) void k_scatter(
    const int* __restrict__ ei, const float* __restrict__ eattr,
    const int* __restrict__ row_ptr, int* __restrict__ cursor,
    int* __restrict__ s_sd, float* __restrict__ s_ea) {
  int e = blockIdx.x * 256 + threadIdx.x;
  if (e >= N_EDGES) return;
  int d = ei[N_EDGES + e];
  int pos = row_ptr[d] + atomicAdd(&cursor[d], 1);
  s_sd[pos] = ei[e] | ((d & (NPB - 1)) << 20);
  s_ea[pos] = eattr[e];
}

// ---------------- embed: h = x*emb_w + emb_b (NF==1) ----------------

__global__ __launch_bounds__(256) void k_embed(
    const float* __restrict__ x, const float* __restrict__ ew,
    const float* __restrict__ eb, float* __restrict__ h) {
  int gid = blockIdx.x * 256 + threadIdx.x;   // N*16 float4 stores
  if (gid >= N_NODES * 16) return;
  int node = gid >> 4;
  int q = gid & 15;
  float xv = x[node];
  float4 w = ((const float4*)ew)[q];
  float4 b = ((const float4*)eb)[q];
  ((float4*)h)[gid] = make_float4(fmaf(xv, w.x, b.x), fmaf(xv, w.y, b.y),
                                  fmaf(xv, w.z, b.z), fmaf(xv, w.w, b.w));
}

// ---------------- per-layer build: z, C/D, ambiguous list ----------------
// Per node: z = h @ W1a + b1 (row in LDS + global for corrections).
// For ea in [0,1): k "always-active" iff min(z_k, z_k+v_k) >= 0 (v = w1b row).
// C = b2 + sum_act z_k*w2[k][:], D = sum_act v_k*w2[k][:] stored interleaved
// per column as float2 {C_j, D_j}. Ambiguous k (knee inside [0,1]) listed
// per node (capacity 64 -> always exact). 64 nodes/block, 4 threads/node.
__global__ __launch_bounds__(256) void k_build(
    const float* __restrict__ h,
    const float* __restrict__ w1,    // [65][64]; row 64 = w1b
    const float* __restrict__ b1,
    const float* __restrict__ w2,    // [64][64]
    const float* __restrict__ b2,
    float* __restrict__ z,           // [N][64]
    float* __restrict__ CD,          // [N][64][2]
    unsigned char* __restrict__ amb, // [N][64]
    int* __restrict__ amb_cnt) {
  __shared__ float hs[64][65];
  __shared__ float zs[64][65];
  const int t = threadIdx.x;
  const int nl = t >> 2;
  const int l4 = t & 3;
  const int node = blockIdx.x * 64 + nl;
  const bool valid = (node < N_NODES);
  const size_t off = (size_t)(valid ? node : 0) * HDIM;
  const int jb = l4 * 16;

  #pragma unroll
  for (int q = 0; q < 4; ++q) {
    float4 hv = ((const float4*)(h + off))[l4 * 4 + q];
    hs[nl][jb + 4*q + 0] = hv.x;
    hs[nl][jb + 4*q + 1] = hv.y;
    hs[nl][jb + 4*q + 2] = hv.z;
    hs[nl][jb + 4*q + 3] = hv.w;
  }
  __syncthreads();

  // z quarter
  float zr[16];
  #pragma unroll
  for (int j = 0; j < 16; ++j) zr[j] = b1[jb + j];
  #pragma unroll 4
  for (int k = 0; k < 64; ++k) {
    float hk = hs[nl][k];
    const float* wr = w1 + k * 64 + jb;
    #pragma unroll
    for (int j = 0; j < 16; ++j) zr[j] = fmaf(hk, wr[j], zr[j]);
  }
  #pragma unroll
  for (int j = 0; j < 16; ++j) zs[nl][jb + j] = zr[j];
  if (valid) {
    #pragma unroll
    for (int q = 0; q < 4; ++q)
      ((float4*)(z + off))[l4 * 4 + q] =
          make_float4(zr[4*q], zr[4*q+1], zr[4*q+2], zr[4*q+3]);
  }
  __syncthreads();

  // C,D quarter
  const float* w1b = w1 + 64 * 64;
  float c[16], d[16];
  #pragma unroll
  for (int j = 0; j < 16; ++j) { c[j] = b2[jb + j]; d[j] = 0.0f; }
  #pragma unroll 4
  for (int k = 0; k < 64; ++k) {
    float zk = zs[nl][k];
    float vk = w1b[k];
    float zv = zk + vk;
    bool act = (fminf(zk, zv) >= 0.0f);
    float cz = act ? zk : 0.0f;
    float cv = act ? vk : 0.0f;
    const float* wr = w2 + k * 64 + jb;
    #pragma unroll
    for (int j = 0; j < 16; ++j) {
      c[j] = fmaf(cz, wr[j], c[j]);
      d[j] = fmaf(cv, wr[j], d[j]);
    }
  }
  if (valid) {
    float4* cdp = (float4*)(CD + (size_t)node * 128);
    #pragma unroll
    for (int j2 = 0; j2 < 8; ++j2)
      cdp[jb / 2 + j2] = make_float4(c[2*j2], d[2*j2], c[2*j2+1], d[2*j2+1]);
  }

  // ambiguous list (serial by thread l4==0)
  if (l4 == 0 && valid) {
    int cnt = 0;
    for (int k = 0; k < 64; ++k) {
      float zk = zs[nl][k];
      float vk = w1b[k];
      float zv = zk + vk;
      if (fminf(zk, zv) < 0.0f && fmaxf(zk, zv) > 0.0f) {
        amb[(size_t)node * 64 + cnt] = (unsigned char)k;
        ++cnt;
      }
    }
    amb_cnt[node] = cnt;
  }
}

// ---------------- fused edge-eval + update ----------------
// 4 waves, 64 dst nodes/block; block edge range split in 4. lane = column.
// Per edge: one coalesced float2 load {C,D} of src, m = C + ea*D, rare exact
// corrections for ambiguous k, running min per lane flushed to LDS atomicMin
// on dst change. Then the update MLP (4 threads/node, s_load weights).
template <int LAST>
__global__ __launch_bounds__(256) void k_layer(
    const int* __restrict__ row_ptr,
    const int* __restrict__ s_sd, const float* __restrict__ s_ea,
    const float2* __restrict__ CDm,
    const float* __restrict__ z,
    const float* __restrict__ w1b, const float* __restrict__ w2,
    const unsigned char* __restrict__ amb, const int* __restrict__ amb_cnt,
    const float* __restrict__ u1w, const float* __restrict__ u1b,
    const float* __restrict__ u2w, const float* __restrict__ u2b,
    const float* __restrict__ fcw, const float* __restrict__ fcb,
    float* __restrict__ h, float* __restrict__ out) {
  __shared__ unsigned acc_u[NPB][65];
  __shared__ float ps[NPB][4];
  float* acc_f = (float*)acc_u;

  const int t = threadIdx.x;
  const int lane = t & 63;
  const int w = __builtin_amdgcn_readfirstlane(t >> 6);
  const int nbase = blockIdx.x * NPB;

  for (int i = t; i < NPB * 65; i += 256) ((unsigned*)acc_u)[i] = 0xFFFFFFFFu;

  const int eb0 = row_ptr[nbase];
  const int eb1 = row_ptr[min(nbase + NPB, N_NODES)];
  const int n = eb1 - eb0;
  const int we0 = eb0 + (n * w) / 4;
  const int we1 = eb0 + (n * (w + 1)) / 4;
  __syncthreads();

  float run = INFINITY;
  int cur = -1;
  for (int e = we0; e < we1; e += 4) {
    const int nb = min(4, we1 - e);
    int sd[4]; float ea4[4]; float2 cd[4];
    #pragma unroll
    for (int i = 0; i < 4; ++i) {
      sd[i] = (i < nb) ? s_sd[e + i] : 0;
      ea4[i] = (i < nb) ? s_ea[e + i] : 0.0f;
    }
    #pragma unroll
    for (int i = 0; i < 4; ++i)
      cd[i] = CDm[(size_t)(sd[i] & 0xFFFFF) * 64 + lane];
    #pragma unroll
    for (int i = 0; i < 4; ++i) {
      if (i >= nb) break;
      const int src = sd[i] & 0xFFFFF;
      const int dl = sd[i] >> 20;
      float m = fmaf(ea4[i], cd[i].y, cd[i].x);
      const int cnt = amb_cnt[src];
      if (cnt) {
        const unsigned char* ap = amb + (size_t)src * 64;
        const float* zrow = z + (size_t)src * 64;
        for (int a = 0; a < cnt; ++a) {
          const int k = ap[a];
          const float tt = fmaf(ea4[i], w1b[k], zrow[k]);
          if (tt > 0.0f) m = fmaf(tt, w2[k * 64 + lane], m);
        }
      }
      if (dl != cur) {
        if (cur >= 0) atomicMin(&acc_u[cur][lane], encMin(run));
        cur = dl; run = INFINITY;
      }
      run = fminf(run, m);
    }
  }
  if (cur >= 0) atomicMin(&acc_u[cur][lane], encMin(run));
  __syncthreads();

  // ================= update: 4 threads/node, 16 cols =================
  const int jq = w * 16;
  const int node = nbase + lane;
  const bool valid = (node < N_NODES);
  const size_t off = (size_t)(valid ? node : 0) * HDIM;

  #pragma unroll
  for (int j = 0; j < 16; ++j) {
    float f = decMin(acc_u[lane][jq + j]);
    if (!isfinite(f)) f = 0.f;
    acc_f[lane * 65 + jq + j] = f;
  }
  __syncthreads();

  // phase 1: acc16 = (u @ U1 + b1)[jq..), u = [h(global), aggr(LDS)]
  float acc[16];
  #pragma unroll
  for (int j = 0; j < 16; ++j) acc[j] = u1b[jq + j];
  {
    const float4* hr = reinterpret_cast<const float4*>(h + off);
    for (int k4 = 0; k4 < 16; ++k4) {
      float4 uv = hr[k4];
      const float* w0 = u1w + (4*k4+0) * 64 + jq;
      const float* w1r = u1w + (4*k4+1) * 64 + jq;
      const float* w2r = u1w + (4*k4+2) * 64 + jq;
      const float* w3 = u1w + (4*k4+3) * 64 + jq;
      #pragma unroll
      for (int j = 0; j < 16; ++j) acc[j] = fmaf(uv.x, w0[j], acc[j]);
      #pragma unroll
      for (int j = 0; j < 16; ++j) acc[j] = fmaf(uv.y, w1r[j], acc[j]);
      #pragma unroll
      for (int j = 0; j < 16; ++j) acc[j] = fmaf(uv.z, w2r[j], acc[j]);
      #pragma unroll
      for (int j = 0; j < 16; ++j) acc[j] = fmaf(uv.w, w3[j], acc[j]);
    }
    #pragma unroll 4
    for (int k = 0; k < 64; ++k) {
      float uk = acc_f[lane * 65 + k];
      const float* wr = u1w + (64 + k) * 64 + jq;
      #pragma unroll
      for (int j = 0; j < 16; ++j) acc[j] = fmaf(uk, wr[j], acc[j]);
    }
  }
  __syncthreads();
  #pragma unroll
  for (int j = 0; j < 16; ++j) acc_f[lane * 65 + jq + j] = fmaxf(acc[j], 0.f);
  __syncthreads();

  // phase 2: hn = (relu(h1) @ U2 + b2)[jq..)
  float hn[16];
  #pragma unroll
  for (int j = 0; j < 16; ++j) hn[j] = u2b[jq + j];
  #pragma unroll 4
  for (int k = 0; k < 64; ++k) {
    float hk = acc_f[lane * 65 + k];
    const float* wr = u2w + k * 64 + jq;
    #pragma unroll
    for (int j = 0; j < 16; ++j) hn[j] = fmaf(hk, wr[j], hn[j]);
  }
  if (valid) {
    #pragma unroll
    for (int v4 = 0; v4 < 4; ++v4)
      reinterpret_cast<float4*>(h + off)[w * 4 + v4] =
          make_float4(hn[4*v4], hn[4*v4+1], hn[4*v4+2], hn[4*v4+3]);
  }

  if (LAST) {
    float s = 0.0f;
    #pragma unroll
    for (int j = 0; j < 16; ++j) s = fmaf(hn[j], fcw[jq + j], s);
    ps[lane][w] = s;
    __syncthreads();
    if (w == 0 && valid)
      out[node] = ps[lane][0] + ps[lane][1] + ps[lane][2] + ps[lane][3] + fcb[0];
  }
}

extern "C" void kernel_launch(void* const* d_in, const int* in_sizes, int n_in,
                              void* d_out, int out_size, void* d_ws, size_t ws_size,
                              hipStream_t stream) {
  const float* x      = (const float*)d_in[0];
  const int*   ei     = (const int*)d_in[1];
  const float* eattr  = (const float*)d_in[2];
  const float* emb_w  = (const float*)d_in[3];
  const float* emb_b  = (const float*)d_in[4];
  const float* msg_w1 = (const float*)d_in[5];
  const float* msg_b1 = (const float*)d_in[6];
  const float* msg_w2 = (const float*)d_in[7];
  const float* msg_b2 = (const float*)d_in[8];
  const float* upd_w1 = (const float*)d_in[9];
  const float* upd_b1 = (const float*)d_in[10];
  const float* upd_w2 = (const float*)d_in[11];
  const float* upd_b2 = (const float*)d_in[12];
  const float* fc_w   = (const float*)d_in[13];
  const float* fc_b   = (const float*)d_in[14];
  float* out = (float*)d_out;

  // workspace layout
  float* h     = (float*)d_ws;                          // N*64
  float* zbuf  = h + (size_t)N_NODES * HDIM;            // N*64
  float* CD    = zbuf + (size_t)N_NODES * HDIM;         // N*128
  float* s_ea  = CD + (size_t)N_NODES * 128;            // E
  int*   s_sd  = (int*)(s_ea + N_EDGES);                // E
  int*   row_ptr = s_sd + N_EDGES;                      // N+1
  int*   deg   = row_ptr + (N_NODES + 1);               // N
  int*   cursor= deg + N_NODES;                         // N
  int*   amb_cnt = cursor + N_NODES;                    // N
  unsigned char* amb = (unsigned char*)(amb_cnt + N_NODES);  // N*64

  const int edgeBlocks = (N_EDGES + 255) / 256;

  // ---- CSR build ----
  k_zero_int<<<(2 * N_NODES + 255) / 256, 256, 0, stream>>>(deg, 2 * N_NODES);
  k_deg_count<<<edgeBlocks, 256, 0, stream>>>(ei, deg);
  k_rowptr<<<1, SCAN_T, 0, stream>>>(deg, row_ptr);
  k_scatter<<<edgeBlocks, 256, 0, stream>>>(ei, eattr, row_ptr, cursor, s_sd, s_ea);

  // ---- embed ----
  k_embed<<<(N_NODES * 16 + 255) / 256, 256, 0, stream>>>(x, emb_w, emb_b, h);

  // ---- layers ----
  for (int l = 0; l < 5; ++l) {
    const float* w1  = msg_w1 + l * 65 * 64;
    const float* b1  = msg_b1 + l * 64;
    const float* w2  = msg_w2 + l * 64 * 64;
    const float* b2  = msg_b2 + l * 64;
    const float* u1w = upd_w1 + l * 128 * 64;
    const float* u1b = upd_b1 + l * 64;
    const float* u2w = upd_w2 + l * 64 * 64;
    const float* u2b = upd_b2 + l * 64;

    k_build<<<LBLOCKS, 256, 0, stream>>>(h, w1, b1, w2, b2, zbuf, CD,
                                         amb, amb_cnt);
    if (l < 4) {
      k_layer<0><<<LBLOCKS, 256, 0, stream>>>(
          row_ptr, s_sd, s_ea, (const float2*)CD, zbuf,
          w1 + 64 * 64, w2, amb, amb_cnt,
          u1w, u1b, u2w, u2b, nullptr, nullptr, h, nullptr);
    } else {
      k_layer<1><<<LBLOCKS, 256, 0, stream>>>(
          row_ptr, s_sd, s_ea, (const float2*)CD, zbuf,
          w1 + 64 * 64, w2, amb, amb_cnt,
          u1w, u1b, u2w, u2b, fc_w, fc_b, h, out);
    }
  }
}

// Round 11
// 2731.640 us; speedup vs baseline: 3.0920x; 3.0920x over previous
//
#include <hip/hip_runtime.h>
#include <math.h>

#define N_NODES 100000
#define N_EDGES 1600000
#define HDIM 64
#define SCAN_T 1024
#define SCAN_CHUNK 98    // ceil(100000/1024)
#define NPB 64           // dst nodes per block
#define LBLOCKS 1563     // ceil(100000/64)
#define BSTR 36          // buf row stride (floats): 144B, 16B-aligned rows

// order-preserving float<->uint map: min-uint == min-float (non-NaN)
__device__ __forceinline__ unsigned encMin(float f) {
  unsigned u = __float_as_uint(f);
  return (u & 0x80000000u) ? ~u : (u | 0x80000000u);
}
__device__ __forceinline__ float decMin(unsigned u) {
  unsigned b = (u & 0x80000000u) ? (u & 0x7FFFFFFFu) : ~u;
  return __uint_as_float(b);
}

// ---------------- CSR build ----------------

__global__ __launch_bounds__(256) void k_zero_int(int* __restrict__ p, int n) {
  int i = blockIdx.x * 256 + threadIdx.x;
  if (i < n) p[i] = 0;
}

__global__ __launch_bounds__(256) void k_deg_count(const int* __restrict__ ei,
                                                   int* __restrict__ deg) {
  int e = blockIdx.x * 256 + threadIdx.x;
  if (e < N_EDGES) atomicAdd(&deg[ei[N_EDGES + e]], 1);
}

// single-block exclusive scan of deg[N] -> row_ptr[N+1]
__global__ __launch_bounds__(SCAN_T) void k_rowptr(const int* __restrict__ deg,
                                                   int* __restrict__ row_ptr) {
  __shared__ int sums[SCAN_T];
  const int t = threadIdx.x;
  const int lo = t * SCAN_CHUNK;
  const int hi = min(lo + SCAN_CHUNK, N_NODES);
  int s = 0;
  for (int i = lo; i < hi; ++i) s += deg[i];
  sums[t] = s;
  __syncthreads();
  for (int off = 1; off < SCAN_T; off <<= 1) {
    int v = (t >= off) ? sums[t - off] : 0;
    __syncthreads();
    sums[t] += v;
    __syncthreads();
  }
  int run = (t == 0) ? 0 : sums[t - 1];
  for (int i = lo; i < hi; ++i) { row_ptr[i] = run; run += deg[i]; }
  if (t == SCAN_T - 1) row_ptr[N_NODES] = run;
}

// pack src (20 bits) | node-local dst (6 bits << 20)
__global__ __launch_bounds__(256) void k_scatter(
    const int* __restrict__ ei, const float* __restrict__ eattr,
    const int* __restrict__ row_ptr, int* __restrict__ cursor,
    int* __restrict__ s_sd, float* __restrict__ s_ea) {
  int e = blockIdx.x * 256 + threadIdx.x;
  if (e >= N_EDGES) return;
  int d = ei[N_EDGES + e];
  int pos = row_ptr[d] + atomicAdd(&cursor[d], 1);
  s_sd[pos] = ei[e] | ((d & (NPB - 1)) << 20);
  s_ea[pos] = eattr[e];
}

// ---------------- embed: h = x*emb_w + emb_b, z = h @ W1a[0] + b1[0] ----------------

__global__ __launch_bounds__(256) void k_embed_z(
    const float* __restrict__ x, const float* __restrict__ emb_w,
    const float* __restrict__ emb_b,
    const float* __restrict__ w1, const float* __restrict__ b1,
    float* __restrict__ h, float* __restrict__ z) {
  __shared__ float hs[64][65];
  const int t = threadIdx.x;
  const int nl = t >> 2;
  const int l4 = t & 3;
  const int i = blockIdx.x * 64 + nl;
  const bool valid = (i < N_NODES);
  const int jbase = l4 * 16;
  const float xv = valid ? x[i] : 0.0f;

  float hv[16];
  #pragma unroll
  for (int jj = 0; jj < 16; ++jj) {
    int j = jbase + jj;
    hv[jj] = fmaf(xv, emb_w[j], emb_b[j]);
    hs[nl][j] = hv[jj];
  }
  if (valid) {
    #pragma unroll
    for (int q = 0; q < 4; ++q)
      reinterpret_cast<float4*>(h + (size_t)i * HDIM)[l4 * 4 + q] =
          make_float4(hv[4*q], hv[4*q+1], hv[4*q+2], hv[4*q+3]);
  }
  __syncthreads();

  float acc[16];
  #pragma unroll
  for (int jj = 0; jj < 16; ++jj) acc[jj] = b1[jbase + jj];
  #pragma unroll 8
  for (int k = 0; k < 64; ++k) {
    float hk = hs[nl][k];
    const float* wr = w1 + k * 64 + jbase;
    #pragma unroll
    for (int jj = 0; jj < 16; ++jj) acc[jj] = fmaf(hk, wr[jj], acc[jj]);
  }
  if (valid) {
    #pragma unroll
    for (int q = 0; q < 4; ++q)
      reinterpret_cast<float4*>(z + (size_t)i * HDIM)[l4 * 4 + q] =
          make_float4(acc[4*q], acc[4*q+1], acc[4*q+2], acc[4*q+3]);
  }
}

// ---------------- fused layer kernel ----------------
// 256 threads = 4 independent waves; 64 dst nodes/block; the block's CSR edge
// range is split in 4 contiguous quarters, one per wave. Per 64-edge batch
// (wave-private, NO barriers):
//   for each k-half (32 k's):
//     stage: 8 lanes/row gather z[src] quad + relu(ea*w1b+z) -> private buf
//     GEMM:  lane = edge, ALL 64 cols in m[64]; hid from own buf row (b64,
//            broadcast-free); w2 rows wave-uniform -> SGPR operands.
//   merge: lane = edge, 64 LDS atomicMin (uint-encoded) into block acc.
// UPDATE (after one barrier): 4 threads/node x 16 cols, s_load weights,
// h1/hn exchanged through acc buffer; phase 3 writes z for next layer.
template <int LAST>
__global__ __launch_bounds__(256) void k_layer(
    const int* __restrict__ row_ptr,
    const int* __restrict__ s_sd, const float* __restrict__ s_ea,
    const float* __restrict__ z_in,
    const float* __restrict__ w1b, const float* __restrict__ w2,
    const float* __restrict__ b2,
    const float* __restrict__ u1w, const float* __restrict__ u1b,
    const float* __restrict__ u2w, const float* __restrict__ u2b,
    const float* __restrict__ w1next, const float* __restrict__ b1next,
    const float* __restrict__ fcw, const float* __restrict__ fcb,
    float* __restrict__ h, float* __restrict__ z_out, float* __restrict__ out) {
  __shared__ float buf[4][64][BSTR];       // per-wave private hid buffer
  __shared__ unsigned acc_u[NPB][65];      // block min-accumulator / exchange
  __shared__ float ps[NPB][4];
  float* acc_f = (float*)acc_u;

  const int t = threadIdx.x;
  const int lane = t & 63;
  const int wv = __builtin_amdgcn_readfirstlane(t >> 6);
  const int nbase = blockIdx.x * NPB;

  // init accumulator to encoded "empty" (decodes to NaN -> 0)
  for (int i = t; i < NPB * 65; i += 256) ((unsigned*)acc_u)[i] = 0xFFFFFFFFu;

  const int eb0 = row_ptr[nbase];
  const int eb1 = row_ptr[min(nbase + NPB, N_NODES)];
  const int n = eb1 - eb0;
  const int we0 = eb0 + (n * wv) / 4;
  const int we1 = eb0 + (n * (wv + 1)) / 4;
  const int rq = lane >> 3;                // row-in-group 0..7
  const int q  = lane & 7;                 // quad 0..7
  float* mybuf = &buf[wv][0][0];
  __syncthreads();   // acc init visible to all waves

  for (int base = we0; base < we1; base += 64) {
    const int cnt = min(64, we1 - base);

    float m[64];
    #pragma unroll
    for (int c = 0; c < 64; ++c) m[c] = b2[c];

    #pragma unroll
    for (int half = 0; half < 2; ++half) {
      const float4 w1bq = ((const float4*)w1b)[half * 8 + q];
      // ---- stage hid k-half for this batch (wave-private) ----
      #pragma unroll
      for (int r = 0; r < 8; ++r) {
        const int row = r * 8 + rq;
        if (row < cnt) {
          const int sd = s_sd[base + row];
          const float ea = s_ea[base + row];
          const int src = sd & 0xFFFFF;
          float4 zq = ((const float4*)(z_in + (size_t)src * HDIM))[half * 8 + q];
          float4 hv;
          hv.x = fmaxf(fmaf(ea, w1bq.x, zq.x), 0.f);
          hv.y = fmaxf(fmaf(ea, w1bq.y, zq.y), 0.f);
          hv.z = fmaxf(fmaf(ea, w1bq.z, zq.z), 0.f);
          hv.w = fmaxf(fmaf(ea, w1bq.w, zq.w), 0.f);
          *(float4*)&mybuf[row * BSTR + q * 4] = hv;
        }
      }
      // ---- GEMM this k-half: lane = edge, all 64 cols, W2 via SGPR ----
      const float* bp = &mybuf[lane * BSTR];
      #pragma unroll 4
      for (int k2 = 0; k2 < 16; ++k2) {
        float2 hq = *(const float2*)&bp[k2 * 2];
        const float* wr0 = w2 + (half * 32 + 2 * k2) * 64;   // wave-uniform
        const float* wr1 = wr0 + 64;
        #pragma unroll
        for (int c = 0; c < 64; ++c) m[c] = fmaf(hq.x, wr0[c], m[c]);
        #pragma unroll
        for (int c = 0; c < 64; ++c) m[c] = fmaf(hq.y, wr1[c], m[c]);
      }
    }
    // ---- merge: encoded LDS atomicMin straight from registers ----
    if (lane < cnt) {
      const int dl = s_sd[base + lane] >> 20;
      #pragma unroll
      for (int c = 0; c < 64; ++c)
        atomicMin(&acc_u[dl][c], encMin(m[c]));
    }
  }
  __syncthreads();

  // ================= update: 4 threads/node, 16 cols =================
  const int jq = wv * 16;                  // wave-uniform col base
  const int node = nbase + lane;
  const bool valid = (node < N_NODES);
  const size_t off = (size_t)(valid ? node : 0) * HDIM;

  // decode own 16 cols in place (NaN from empty segments -> 0)
  #pragma unroll
  for (int j = 0; j < 16; ++j) {
    float f = decMin(acc_u[lane][jq + j]);
    if (!isfinite(f)) f = 0.f;
    acc_f[lane * 65 + jq + j] = f;
  }
  __syncthreads();

  // ---- phase 1: acc16 = (u @ U1 + b1)[jq..), u = [h(global), aggr(LDS)] ----
  float acc[16];
  #pragma unroll
  for (int j = 0; j < 16; ++j) acc[j] = u1b[jq + j];
  {
    const float4* hr = reinterpret_cast<const float4*>(h + off);
    for (int k4 = 0; k4 < 16; ++k4) {
      float4 uv = hr[k4];
      const float* w0 = u1w + (4*k4+0) * 64 + jq;
      const float* w1r = u1w + (4*k4+1) * 64 + jq;
      const float* w2r = u1w + (4*k4+2) * 64 + jq;
      const float* w3 = u1w + (4*k4+3) * 64 + jq;
      #pragma unroll
      for (int j = 0; j < 16; ++j) acc[j] = fmaf(uv.x, w0[j], acc[j]);
      #pragma unroll
      for (int j = 0; j < 16; ++j) acc[j] = fmaf(uv.y, w1r[j], acc[j]);
      #pragma unroll
      for (int j = 0; j < 16; ++j) acc[j] = fmaf(uv.z, w2r[j], acc[j]);
      #pragma unroll
      for (int j = 0; j < 16; ++j) acc[j] = fmaf(uv.w, w3[j], acc[j]);
    }
    #pragma unroll 4
    for (int k = 0; k < 64; ++k) {
      float uk = acc_f[lane * 65 + k];
      const float* wr = u1w + (64 + k) * 64 + jq;
      #pragma unroll
      for (int j = 0; j < 16; ++j) acc[j] = fmaf(uk, wr[j], acc[j]);
    }
  }
  __syncthreads();   // phase-1 LDS reads done before overwrite
  #pragma unroll
  for (int j = 0; j < 16; ++j) acc_f[lane * 65 + jq + j] = fmaxf(acc[j], 0.f);
  __syncthreads();

  // ---- phase 2: hn = (relu(h1) @ U2 + b2)[jq..) ----
  float hn[16];
  #pragma unroll
  for (int j = 0; j < 16; ++j) hn[j] = u2b[jq + j];
  #pragma unroll 4
  for (int k = 0; k < 64; ++k) {
    float hk = acc_f[lane * 65 + k];
    const float* wr = u2w + k * 64 + jq;
    #pragma unroll
    for (int j = 0; j < 16; ++j) hn[j] = fmaf(hk, wr[j], hn[j]);
  }
  if (valid) {
    #pragma unroll
    for (int v4 = 0; v4 < 4; ++v4)
      reinterpret_cast<float4*>(h + off)[wv * 4 + v4] =
          make_float4(hn[4*v4], hn[4*v4+1], hn[4*v4+2], hn[4*v4+3]);
  }

  if (LAST) {
    float s = 0.0f;
    #pragma unroll
    for (int j = 0; j < 16; ++j) s = fmaf(hn[j], fcw[jq + j], s);
    ps[lane][wv] = s;
    __syncthreads();
    if (wv == 0 && valid)
      out[node] = ps[lane][0] + ps[lane][1] + ps[lane][2] + ps[lane][3] + fcb[0];
  } else {
    __syncthreads();   // phase-2 LDS reads done
    #pragma unroll
    for (int j = 0; j < 16; ++j) acc_f[lane * 65 + jq + j] = hn[j];
    __syncthreads();
    // ---- phase 3: z_next = h_new @ W1a_next + b1_next ----
    float zz[16];
    #pragma unroll
    for (int j = 0; j < 16; ++j) zz[j] = b1next[jq + j];
    #pragma unroll 4
    for (int k = 0; k < 64; ++k) {
      float hk = acc_f[lane * 65 + k];
      const float* wr = w1next + k * 64 + jq;
      #pragma unroll
      for (int j = 0; j < 16; ++j) zz[j] = fmaf(hk, wr[j], zz[j]);
    }
    if (valid) {
      #pragma unroll
      for (int v4 = 0; v4 < 4; ++v4)
        reinterpret_cast<float4*>(z_out + off)[wv * 4 + v4] =
            make_float4(zz[4*v4], zz[4*v4+1], zz[4*v4+2], zz[4*v4+3]);
    }
  }
}

extern "C" void kernel_launch(void* const* d_in, const int* in_sizes, int n_in,
                              void* d_out, int out_size, void* d_ws, size_t ws_size,
                              hipStream_t stream) {
  const float* x      = (const float*)d_in[0];
  const int*   ei     = (const int*)d_in[1];
  const float* eattr  = (const float*)d_in[2];
  const float* emb_w  = (const float*)d_in[3];
  const float* emb_b  = (const float*)d_in[4];
  const float* msg_w1 = (const float*)d_in[5];
  const float* msg_b1 = (const float*)d_in[6];
  const float* msg_w2 = (const float*)d_in[7];
  const float* msg_b2 = (const float*)d_in[8];
  const float* upd_w1 = (const float*)d_in[9];
  const float* upd_b1 = (const float*)d_in[10];
  const float* upd_w2 = (const float*)d_in[11];
  const float* upd_b2 = (const float*)d_in[12];
  const float* fc_w   = (const float*)d_in[13];
  const float* fc_b   = (const float*)d_in[14];
  float* out = (float*)d_out;

  // workspace layout
  float* h     = (float*)d_ws;                          // N*64
  float* zA    = h + (size_t)N_NODES * HDIM;            // N*64
  float* zB    = zA + (size_t)N_NODES * HDIM;           // N*64
  float* s_ea  = zB + (size_t)N_NODES * HDIM;           // E
  int*   s_sd  = (int*)(s_ea + N_EDGES);                // E
  int*   row_ptr = s_sd + N_EDGES;                      // N+1
  int*   deg   = row_ptr + (N_NODES + 1);               // N
  int*   cursor= deg + N_NODES;                         // N (contiguous w/ deg)

  const int nodeBlocks64 = (N_NODES + 63) / 64;
  const int edgeBlocks = (N_EDGES + 255) / 256;

  // ---- CSR build ----
  k_zero_int<<<(2 * N_NODES + 255) / 256, 256, 0, stream>>>(deg, 2 * N_NODES);
  k_deg_count<<<edgeBlocks, 256, 0, stream>>>(ei, deg);
  k_rowptr<<<1, SCAN_T, 0, stream>>>(deg, row_ptr);
  k_scatter<<<edgeBlocks, 256, 0, stream>>>(ei, eattr, row_ptr, cursor, s_sd, s_ea);

  // ---- embed + fused layers ----
  k_embed_z<<<nodeBlocks64, 256, 0, stream>>>(x, emb_w, emb_b, msg_w1, msg_b1, h, zA);

  float* zin = zA;
  float* zout = zB;
  for (int l = 0; l < 5; ++l) {
    const float* w1b = msg_w1 + l * 65 * 64 + 64 * 64;  // row 64: edge_attr coeffs
    const float* w2  = msg_w2 + l * 64 * 64;
    const float* b2  = msg_b2 + l * 64;
    const float* u1w = upd_w1 + l * 128 * 64;
    const float* u1b = upd_b1 + l * 64;
    const float* u2w = upd_w2 + l * 64 * 64;
    const float* u2b = upd_b2 + l * 64;
    if (l < 4) {
      k_layer<0><<<LBLOCKS, 256, 0, stream>>>(
          row_ptr, s_sd, s_ea, zin,
          w1b, w2, b2, u1w, u1b, u2w, u2b,
          msg_w1 + (l + 1) * 65 * 64, msg_b1 + (l + 1) * 64,
          nullptr, nullptr,
          h, zout, nullptr);
      float* tmp = zin; zin = zout; zout = tmp;
    } else {
      k_layer<1><<<LBLOCKS, 256, 0, stream>>>(
          row_ptr, s_sd, s_ea, zin,
          w1b, w2, b2, u1w, u1b, u2w, u2b,
          nullptr, nullptr,
          fc_w, fc_b,
          h, nullptr, out);
    }
  }
}

// Round 12
// 2542.640 us; speedup vs baseline: 3.3218x; 1.0743x over previous
//
#include <hip/hip_runtime.h>
#include <math.h>

#define N_NODES 100000
#define N_EDGES 1600000
#define HDIM 64
#define SCAN_T 1024
#define SCAN_CHUNK 98    // ceil(100000/1024)
#define NPB 64           // dst nodes per block
#define LBLOCKS 1563     // ceil(100000/64)
#define BSTR 34          // buf row stride (floats): 34%32==2 -> 2-way banks (free)

// order-preserving float<->uint map: min-uint == min-float (non-NaN)
__device__ __forceinline__ unsigned encMin(float f) {
  unsigned u = __float_as_uint(f);
  return (u & 0x80000000u) ? ~u : (u | 0x80000000u);
}
__device__ __forceinline__ float decMin(unsigned u) {
  unsigned b = (u & 0x80000000u) ? (u & 0x7FFFFFFFu) : ~u;
  return __uint_as_float(b);
}

// ---------------- CSR build ----------------

__global__ __launch_bounds__(256) void k_zero_int(int* __restrict__ p, int n) {
  int i = blockIdx.x * 256 + threadIdx.x;
  if (i < n) p[i] = 0;
}

__global__ __launch_bounds__(256) void k_deg_count(const int* __restrict__ ei,
                                                   int* __restrict__ deg) {
  int e = blockIdx.x * 256 + threadIdx.x;
  if (e < N_EDGES) atomicAdd(&deg[ei[N_EDGES + e]], 1);
}

// single-block exclusive scan of deg[N] -> row_ptr[N+1]
__global__ __launch_bounds__(SCAN_T) void k_rowptr(const int* __restrict__ deg,
                                                   int* __restrict__ row_ptr) {
  __shared__ int sums[SCAN_T];
  const int t = threadIdx.x;
  const int lo = t * SCAN_CHUNK;
  const int hi = min(lo + SCAN_CHUNK, N_NODES);
  int s = 0;
  for (int i = lo; i < hi; ++i) s += deg[i];
  sums[t] = s;
  __syncthreads();
  for (int off = 1; off < SCAN_T; off <<= 1) {
    int v = (t >= off) ? sums[t - off] : 0;
    __syncthreads();
    sums[t] += v;
    __syncthreads();
  }
  int run = (t == 0) ? 0 : sums[t - 1];
  for (int i = lo; i < hi; ++i) { row_ptr[i] = run; run += deg[i]; }
  if (t == SCAN_T - 1) row_ptr[N_NODES] = run;
}

// pack src (20 bits) | node-local dst (6 bits << 20)
__global__ __launch_bounds__(256) void k_scatter(
    const int* __restrict__ ei, const float* __restrict__ eattr,
    const int* __restrict__ row_ptr, int* __restrict__ cursor,
    int* __restrict__ s_sd, float* __restrict__ s_ea) {
  int e = blockIdx.x * 256 + threadIdx.x;
  if (e >= N_EDGES) return;
  int d = ei[N_EDGES + e];
  int pos = row_ptr[d] + atomicAdd(&cursor[d], 1);
  s_sd[pos] = ei[e] | ((d & (NPB - 1)) << 20);
  s_ea[pos] = eattr[e];
}

// ---------------- embed: h = x*emb_w + emb_b, z = h @ W1a[0] + b1[0] ----------------

__global__ __launch_bounds__(256) void k_embed_z(
    const float* __restrict__ x, const float* __restrict__ emb_w,
    const float* __restrict__ emb_b,
    const float* __restrict__ w1, const float* __restrict__ b1,
    float* __restrict__ h, float* __restrict__ z) {
  __shared__ float hs[64][65];
  const int t = threadIdx.x;
  const int nl = t >> 2;
  const int l4 = t & 3;
  const int i = blockIdx.x * 64 + nl;
  const bool valid = (i < N_NODES);
  const int jbase = l4 * 16;
  const float xv = valid ? x[i] : 0.0f;

  float hv[16];
  #pragma unroll
  for (int jj = 0; jj < 16; ++jj) {
    int j = jbase + jj;
    hv[jj] = fmaf(xv, emb_w[j], emb_b[j]);
    hs[nl][j] = hv[jj];
  }
  if (valid) {
    #pragma unroll
    for (int q = 0; q < 4; ++q)
      reinterpret_cast<float4*>(h + (size_t)i * HDIM)[l4 * 4 + q] =
          make_float4(hv[4*q], hv[4*q+1], hv[4*q+2], hv[4*q+3]);
  }
  __syncthreads();

  float acc[16];
  #pragma unroll
  for (int jj = 0; jj < 16; ++jj) acc[jj] = b1[jbase + jj];
  #pragma unroll 8
  for (int k = 0; k < 64; ++k) {
    float hk = hs[nl][k];
    const float* wr = w1 + k * 64 + jbase;
    #pragma unroll
    for (int jj = 0; jj < 16; ++jj) acc[jj] = fmaf(hk, wr[jj], acc[jj]);
  }
  if (valid) {
    #pragma unroll
    for (int q = 0; q < 4; ++q)
      reinterpret_cast<float4*>(z + (size_t)i * HDIM)[l4 * 4 + q] =
          make_float4(acc[4*q], acc[4*q+1], acc[4*q+2], acc[4*q+3]);
  }
}

// ---------------- fused layer kernel ----------------
// 256 threads = 4 independent waves; 64 dst nodes/block; block's CSR edge
// range split in 4 contiguous quarters, one per wave. Per 64-edge batch
// (wave-private buf, NO block barriers in the loop):
//   for each k-half: stage hid (8 lanes/row, float2 writes, stride 34 ->
//     2-way banks) ; GEMM lane=edge, m[64], W2 rows wave-uniform -> SGPR.
//   merge (two col-half passes, round-7 pattern): writeback m half to own
//     row (b64, 2-way), then lane=(col,edge-group) serial scan, dst via
//     __shfl of preloaded dl, flush to acc via atomicMin on segment change
//     only (~3/pass, all-distinct addresses -> conflict-free).
// UPDATE (after one barrier): 4 threads/node x 16 cols, s_load weights.
template <int LAST>
__global__ __launch_bounds__(256) void k_layer(
    const int* __restrict__ row_ptr,
    const int* __restrict__ s_sd, const float* __restrict__ s_ea,
    const float* __restrict__ z_in,
    const float* __restrict__ w1b, const float* __restrict__ w2,
    const float* __restrict__ b2,
    const float* __restrict__ u1w, const float* __restrict__ u1b,
    const float* __restrict__ u2w, const float* __restrict__ u2b,
    const float* __restrict__ w1next, const float* __restrict__ b1next,
    const float* __restrict__ fcw, const float* __restrict__ fcb,
    float* __restrict__ h, float* __restrict__ z_out, float* __restrict__ out) {
  __shared__ float buf[4][64][BSTR];       // per-wave private hid/msg buffer
  __shared__ unsigned acc_u[NPB][65];      // block min-accumulator / exchange
  __shared__ float ps[NPB][4];
  float* acc_f = (float*)acc_u;

  const int t = threadIdx.x;
  const int lane = t & 63;
  const int wv = __builtin_amdgcn_readfirstlane(t >> 6);
  const int nbase = blockIdx.x * NPB;

  // init accumulator to encoded "empty" (decodes to NaN -> 0)
  for (int i = t; i < NPB * 65; i += 256) ((unsigned*)acc_u)[i] = 0xFFFFFFFFu;

  const int eb0 = row_ptr[nbase];
  const int eb1 = row_ptr[min(nbase + NPB, N_NODES)];
  const int n = eb1 - eb0;
  const int we0 = eb0 + (n * wv) / 4;
  const int we1 = eb0 + (n * (wv + 1)) / 4;
  const int rq = lane >> 3;                // row-in-group 0..7
  const int q  = lane & 7;                 // quad 0..7
  const int eg = lane >> 5;                // edge-group for merge scan (0,1)
  const int cl = lane & 31;                // col within half for merge scan
  float* mybuf = &buf[wv][0][0];
  __syncthreads();   // acc init visible to all waves

  for (int base = we0; base < we1; base += 64) {
    const int cnt = min(64, we1 - base);
    const int sdv = (lane < cnt) ? s_sd[base + lane] : 0;
    const int dlv = sdv >> 20;             // per-lane dst (node-local), lane=edge

    float m[64];
    #pragma unroll
    for (int c = 0; c < 64; ++c) m[c] = b2[c];

    #pragma unroll
    for (int half = 0; half < 2; ++half) {
      const float4 w1bq = ((const float4*)w1b)[half * 8 + q];
      // ---- stage hid k-half (wave-private; intra-wave ordering) ----
      #pragma unroll
      for (int r = 0; r < 8; ++r) {
        const int row = r * 8 + rq;
        if (row < cnt) {
          const int sd = s_sd[base + row];
          const float ea = s_ea[base + row];
          const int src = sd & 0xFFFFF;
          float4 zq = ((const float4*)(z_in + (size_t)src * HDIM))[half * 8 + q];
          float2 h0, h1;
          h0.x = fmaxf(fmaf(ea, w1bq.x, zq.x), 0.f);
          h0.y = fmaxf(fmaf(ea, w1bq.y, zq.y), 0.f);
          h1.x = fmaxf(fmaf(ea, w1bq.z, zq.z), 0.f);
          h1.y = fmaxf(fmaf(ea, w1bq.w, zq.w), 0.f);
          *(float2*)&mybuf[row * BSTR + q * 4]     = h0;
          *(float2*)&mybuf[row * BSTR + q * 4 + 2] = h1;
        }
      }
      // ---- GEMM this k-half: lane = edge, all 64 cols, W2 via SGPR ----
      const float* bp = &mybuf[lane * BSTR];
      #pragma unroll 4
      for (int k2 = 0; k2 < 16; ++k2) {
        float2 hq = *(const float2*)&bp[k2 * 2];
        const float* wr0 = w2 + (half * 32 + 2 * k2) * 64;   // wave-uniform
        const float* wr1 = wr0 + 64;
        #pragma unroll
        for (int c = 0; c < 64; ++c) m[c] = fmaf(hq.x, wr0[c], m[c]);
        #pragma unroll
        for (int c = 0; c < 64; ++c) m[c] = fmaf(hq.y, wr1[c], m[c]);
      }
    }

    // ---- merge: two col-half passes (writeback + col-scan, conflict-free) ----
    #pragma unroll
    for (int ch = 0; ch < 2; ++ch) {
      asm volatile("s_waitcnt lgkmcnt(0)" ::: "memory");  // prior reads done
      if (lane < cnt) {
        #pragma unroll
        for (int j2 = 0; j2 < 16; ++j2)
          *(float2*)&mybuf[lane * BSTR + 2 * j2] =
              make_float2(m[ch * 32 + 2 * j2], m[ch * 32 + 2 * j2 + 1]);
      }
      asm volatile("s_waitcnt lgkmcnt(0)" ::: "memory");  // writeback visible
      float run = INFINITY;
      int cur = -1;
      for (int i = 0; i < 32; ++i) {
        const int e = eg * 32 + i;
        if (e >= cnt) break;
        const int dl = __shfl(dlv, e);
        const float v = mybuf[e * BSTR + cl];
        if (dl != cur) {
          if (cur >= 0) atomicMin(&acc_u[cur][ch * 32 + cl], encMin(run));
          cur = dl; run = INFINITY;
        }
        run = fminf(run, v);
      }
      if (cur >= 0) atomicMin(&acc_u[cur][ch * 32 + cl], encMin(run));
    }
  }
  __syncthreads();

  // ================= update: 4 threads/node, 16 cols =================
  const int jq = wv * 16;                  // wave-uniform col base
  const int node = nbase + lane;
  const bool valid = (node < N_NODES);
  const size_t off = (size_t)(valid ? node : 0) * HDIM;

  // decode own 16 cols in place (NaN from empty segments -> 0)
  #pragma unroll
  for (int j = 0; j < 16; ++j) {
    float f = decMin(acc_u[lane][jq + j]);
    if (!isfinite(f)) f = 0.f;
    acc_f[lane * 65 + jq + j] = f;
  }
  __syncthreads();

  // ---- phase 1: acc16 = (u @ U1 + b1)[jq..), u = [h(global), aggr(LDS)] ----
  float acc[16];
  #pragma unroll
  for (int j = 0; j < 16; ++j) acc[j] = u1b[jq + j];
  {
    const float4* hr = reinterpret_cast<const float4*>(h + off);
    for (int k4 = 0; k4 < 16; ++k4) {
      float4 uv = hr[k4];
      const float* w0 = u1w + (4*k4+0) * 64 + jq;
      const float* w1r = u1w + (4*k4+1) * 64 + jq;
      const float* w2r = u1w + (4*k4+2) * 64 + jq;
      const float* w3 = u1w + (4*k4+3) * 64 + jq;
      #pragma unroll
      for (int j = 0; j < 16; ++j) acc[j] = fmaf(uv.x, w0[j], acc[j]);
      #pragma unroll
      for (int j = 0; j < 16; ++j) acc[j] = fmaf(uv.y, w1r[j], acc[j]);
      #pragma unroll
      for (int j = 0; j < 16; ++j) acc[j] = fmaf(uv.z, w2r[j], acc[j]);
      #pragma unroll
      for (int j = 0; j < 16; ++j) acc[j] = fmaf(uv.w, w3[j], acc[j]);
    }
    #pragma unroll 4
    for (int k = 0; k < 64; ++k) {
      float uk = acc_f[lane * 65 + k];
      const float* wr = u1w + (64 + k) * 64 + jq;
      #pragma unroll
      for (int j = 0; j < 16; ++j) acc[j] = fmaf(uk, wr[j], acc[j]);
    }
  }
  __syncthreads();   // phase-1 LDS reads done before overwrite
  #pragma unroll
  for (int j = 0; j < 16; ++j) acc_f[lane * 65 + jq + j] = fmaxf(acc[j], 0.f);
  __syncthreads();

  // ---- phase 2: hn = (relu(h1) @ U2 + b2)[jq..) ----
  float hn[16];
  #pragma unroll
  for (int j = 0; j < 16; ++j) hn[j] = u2b[jq + j];
  #pragma unroll 4
  for (int k = 0; k < 64; ++k) {
    float hk = acc_f[lane * 65 + k];
    const float* wr = u2w + k * 64 + jq;
    #pragma unroll
    for (int j = 0; j < 16; ++j) hn[j] = fmaf(hk, wr[j], hn[j]);
  }
  if (valid) {
    #pragma unroll
    for (int v4 = 0; v4 < 4; ++v4)
      reinterpret_cast<float4*>(h + off)[wv * 4 + v4] =
          make_float4(hn[4*v4], hn[4*v4+1], hn[4*v4+2], hn[4*v4+3]);
  }

  if (LAST) {
    float s = 0.0f;
    #pragma unroll
    for (int j = 0; j < 16; ++j) s = fmaf(hn[j], fcw[jq + j], s);
    ps[lane][wv] = s;
    __syncthreads();
    if (wv == 0 && valid)
      out[node] = ps[lane][0] + ps[lane][1] + ps[lane][2] + ps[lane][3] + fcb[0];
  } else {
    __syncthreads();   // phase-2 LDS reads done
    #pragma unroll
    for (int j = 0; j < 16; ++j) acc_f[lane * 65 + jq + j] = hn[j];
    __syncthreads();
    // ---- phase 3: z_next = h_new @ W1a_next + b1_next ----
    float zz[16];
    #pragma unroll
    for (int j = 0; j < 16; ++j) zz[j] = b1next[jq + j];
    #pragma unroll 4
    for (int k = 0; k < 64; ++k) {
      float hk = acc_f[lane * 65 + k];
      const float* wr = w1next + k * 64 + jq;
      #pragma unroll
      for (int j = 0; j < 16; ++j) zz[j] = fmaf(hk, wr[j], zz[j]);
    }
    if (valid) {
      #pragma unroll
      for (int v4 = 0; v4 < 4; ++v4)
        reinterpret_cast<float4*>(z_out + off)[wv * 4 + v4] =
            make_float4(zz[4*v4], zz[4*v4+1], zz[4*v4+2], zz[4*v4+3]);
    }
  }
}

extern "C" void kernel_launch(void* const* d_in, const int* in_sizes, int n_in,
                              void* d_out, int out_size, void* d_ws, size_t ws_size,
                              hipStream_t stream) {
  const float* x      = (const float*)d_in[0];
  const int*   ei     = (const int*)d_in[1];
  const float* eattr  = (const float*)d_in[2];
  const float* emb_w  = (const float*)d_in[3];
  const float* emb_b  = (const float*)d_in[4];
  const float* msg_w1 = (const float*)d_in[5];
  const float* msg_b1 = (const float*)d_in[6];
  const float* msg_w2 = (const float*)d_in[7];
  const float* msg_b2 = (const float*)d_in[8];
  const float* upd_w1 = (const float*)d_in[9];
  const float* upd_b1 = (const float*)d_in[10];
  const float* upd_w2 = (const float*)d_in[11];
  const float* upd_b2 = (const float*)d_in[12];
  const float* fc_w   = (const float*)d_in[13];
  const float* fc_b   = (const float*)d_in[14];
  float* out = (float*)d_out;

  // workspace layout
  float* h     = (float*)d_ws;                          // N*64
  float* zA    = h + (size_t)N_NODES * HDIM;            // N*64
  float* zB    = zA + (size_t)N_NODES * HDIM;           // N*64
  float* s_ea  = zB + (size_t)N_NODES * HDIM;           // E
  int*   s_sd  = (int*)(s_ea + N_EDGES);                // E
  int*   row_ptr = s_sd + N_EDGES;                      // N+1
  int*   deg   = row_ptr + (N_NODES + 1);               // N
  int*   cursor= deg + N_NODES;                         // N (contiguous w/ deg)

  const int nodeBlocks64 = (N_NODES + 63) / 64;
  const int edgeBlocks = (N_EDGES + 255) / 256;

  // ---- CSR build ----
  k_zero_int<<<(2 * N_NODES + 255) / 256, 256, 0, stream>>>(deg, 2 * N_NODES);
  k_deg_count<<<edgeBlocks, 256, 0, stream>>>(ei, deg);
  k_rowptr<<<1, SCAN_T, 0, stream>>>(deg, row_ptr);
  k_scatter<<<edgeBlocks, 256, 0, stream>>>(ei, eattr, row_ptr, cursor, s_sd, s_ea);

  // ---- embed + fused layers ----
  k_embed_z<<<nodeBlocks64, 256, 0, stream>>>(x, emb_w, emb_b, msg_w1, msg_b1, h, zA);

  float* zin = zA;
  float* zout = zB;
  for (int l = 0; l < 5; ++l) {
    const float* w1b = msg_w1 + l * 65 * 64 + 64 * 64;  // row 64: edge_attr coeffs
    const float* w2  = msg_w2 + l * 64 * 64;
    const float* b2  = msg_b2 + l * 64;
    const float* u1w = upd_w1 + l * 128 * 64;
    const float* u1b = upd_b1 + l * 64;
    const float* u2w = upd_w2 + l * 64 * 64;
    const float* u2b = upd_b2 + l * 64;
    if (l < 4) {
      k_layer<0><<<LBLOCKS, 256, 0, stream>>>(
          row_ptr, s_sd, s_ea, zin,
          w1b, w2, b2, u1w, u1b, u2w, u2b,
          msg_w1 + (l + 1) * 65 * 64, msg_b1 + (l + 1) * 64,
          nullptr, nullptr,
          h, zout, nullptr);
      float* tmp = zin; zin = zout; zout = tmp;
    } else {
      k_layer<1><<<LBLOCKS, 256, 0, stream>>>(
          row_ptr, s_sd, s_ea, zin,
          w1b, w2, b2, u1w, u1b, u2w, u2b,
          nullptr, nullptr,
          fc_w, fc_b,
          h, nullptr, out);
    }
  }
}